// Round 6
// baseline (180.727 us; speedup 1.0000x reference)
//
#include <hip/hip_runtime.h>

// Problem constants (from reference)
#define N_  16
#define H_  512
#define W_  512
#define F_  13776
#define V_  6890
// total pixels = N*H*W = 4,194,304 ; pairs = 2,097,152 = 8192 blocks * 256 threads
//
// Dtype model (established rounds 0-5, all observations explained):
//   pix_to_face      : int32   (R3 int64 read -> 2x OOB -> core dump)
//   bary_coords      : fp32    (read as bf16 -> NaN in R0/R5)
//   faces            : int32
//   verts_scene_flow : fp32    (read as bf16 -> NaN in R4)
//   output           : fp32    (R2 wrote bf16-packed -> harness fp32 readback
//                               gave the shuffled-compare 9.83 signature;
//                               threshold 0.1525 == 2% * max|ref| 7.625)

__device__ __forceinline__ void shade_pixel(
    int fid, float w0, float w1, float w2,
    const int*   __restrict__ faces,
    const float* __restrict__ verts,
    float& ox, float& oy, float& oz)
{
    const bool valid = fid >= 0;
    const int sf   = valid ? fid : 0;
    const int mesh = sf / F_;            // compile-time magic multiply
    const int loc  = sf - mesh * F_;
    const int vb   = mesh * V_;
    const int fb   = loc * 3;
    const int i0 = (faces[fb + 0] + vb) * 3;
    const int i1 = (faces[fb + 1] + vb) * 3;
    const int i2 = (faces[fb + 2] + vb) * 3;
    const float a0x = verts[i0], a0y = verts[i0 + 1], a0z = verts[i0 + 2];
    const float a1x = verts[i1], a1y = verts[i1 + 1], a1z = verts[i1 + 2];
    const float a2x = verts[i2], a2y = verts[i2 + 1], a2z = verts[i2 + 2];
    ox = w0 * a0x + w1 * a1x + w2 * a2x;
    oy = w0 * a0y + w1 * a1y + w2 * a2y;
    oz = w0 * a0z + w1 * a1z + w2 * a2z;
    if (!valid) { ox = 0.f; oy = 0.f; oz = 0.f; }
}

__global__ __launch_bounds__(256) void OpticalFlowShader_kernel(
    const int*   __restrict__ ptf,    // [N,H,W,1] int32
    const float* __restrict__ bary,   // [N,H,W,1,3] float32
    const int*   __restrict__ faces,  // [F,3] int32
    const float* __restrict__ verts,  // [N,V,3] float32
    float*       __restrict__ out)    // [N,H,W,3] float32
{
    const int t = blockIdx.x * 256 + threadIdx.x;   // pair index, exact fit
    const int p0 = 2 * t;
    const int p1 = p0 + 1;

    // face ids: 8B aligned int2 (int32 data)
    const int2 pf = ((const int2*)ptf)[t];

    // bary: 6 floats = 24 bytes at t*24, 8B-aligned float2 loads
    const float2* bp = (const float2*)bary;
    const float2 b0 = bp[t * 3 + 0];   // w00, w01
    const float2 b1 = bp[t * 3 + 1];   // w02, w10
    const float2 b2 = bp[t * 3 + 2];   // w11, w12

    float r0x, r0y, r0z, r1x, r1y, r1z;
    shade_pixel(pf.x, b0.x, b0.y, b1.x, faces, verts, r0x, r0y, r0z);
    shade_pixel(pf.y, b1.y, b2.x, b2.y, faces, verts, r1x, r1y, r1z);

    // mesh grid: channel0 = gx varies with w, channel1 = gy varies with h
    // linspace(-1,1,512) step = 2/511
    const float step = 2.0f / 511.0f;
    const int w0i = p0 & (W_ - 1);
    const int h0i = (p0 >> 9) & (H_ - 1);
    const int w1i = p1 & (W_ - 1);
    const int h1i = (p1 >> 9) & (H_ - 1);
    r0x += (float)w0i * step - 1.0f;
    r0y += (float)h0i * step - 1.0f;
    r1x += (float)w1i * step - 1.0f;
    r1y += (float)h1i * step - 1.0f;

    // fp32 output: 6 floats = 24 bytes per pair, 3 aligned float2 stores
    float2* op = (float2*)out;
    op[t * 3 + 0] = make_float2(r0x, r0y);
    op[t * 3 + 1] = make_float2(r0z, r1x);
    op[t * 3 + 2] = make_float2(r1y, r1z);
}

extern "C" void kernel_launch(void* const* d_in, const int* in_sizes, int n_in,
                              void* d_out, int out_size, void* d_ws, size_t ws_size,
                              hipStream_t stream) {
    const int*   ptf   = (const int*)d_in[0];
    const float* bary  = (const float*)d_in[1];
    const int*   faces = (const int*)d_in[2];
    const float* verts = (const float*)d_in[3];
    float*       out   = (float*)d_out;

    // pairs = N*H*W/2 = 2,097,152 -> 8192 blocks of 256
    const int pairs  = (N_ * H_ * W_) / 2;
    const int blocks = pairs / 256;
    OpticalFlowShader_kernel<<<blocks, 256, 0, stream>>>(ptf, bary, faces, verts, out);
}